// Round 1
// baseline (629.474 us; speedup 1.0000x reference)
//
#include <hip/hip_runtime.h>

// Sequential 5x5 cellular scatter over 48x48 grids, 8192 batches, fp32.
// Reformulated as: (1) gather-form forward recurrence over the 1936 interior
// cells, scheduled on anti-diagonal wavefronts t(y,x) = (y-2) + 3*(x-2)
// (173 barrier steps, same-t cells are >=3 apart so they commute exactly);
// (2) fully-parallel finalize: out = center-term + later-neighbor scatters
// (all-interior-neighbor scatters for border cells).
//
// Workgroup: 8 batch grids in LDS (stride 2308 floats to avoid 32-bank
// aliasing), 128 threads = 8 batches x 16 wavefront slots. 73.9 KB LDS ->
// 2 blocks/CU, 1024 blocks = 2 occupancy rounds.

#define SZ 48
#define DP 2
#define NC (SZ * SZ)      // 2304
#define NB 8              // batches per workgroup
#define GS 2308           // LDS row stride (floats); 2308 % 32 == 4
#define NSTEP 173         // max t = 43 + 3*43 = 172
#define NT 128

__device__ __forceinline__ bool is_in(int v) {
    // v in [2, 45]
    return (unsigned)(v - DP) <= (unsigned)(SZ - 2 * DP - 1);
}

__global__ __launch_bounds__(NT)
void ca_kernel(const float* __restrict__ in, const float* __restrict__ w,
               float* __restrict__ out)
{
    extern __shared__ float g[];   // NB * GS floats
    const int tid = threadIdx.x;
    const int b0  = blockIdx.x * NB;

    // ---- load 8 grids into LDS (coalesced) ----
    for (int i = tid; i < NB * NC; i += NT) {
        int b = i / NC, c = i - b * NC;
        g[b * GS + c] = in[(b0 + b) * NC + c];
    }
    __syncthreads();

    const int bl = tid & (NB - 1);   // batch lane 0..7
    const int s  = tid >> 3;         // wavefront slot 0..15

    // earlier-neighbor offsets (processed before (y,x) in x-major order)
    const int E_DY[12] = {-2,-1, 0, 1, 2, -2,-1, 0, 1, 2, -2,-1};
    const int E_DX[12] = {-2,-2,-2,-2,-2, -1,-1,-1,-1,-1,  0, 0};

    // ---- forward wavefront: V(y,x) = in + sum_earlier V(n)*w_n[p-n+2] ----
    for (int t = 0; t < NSTEP; ++t) {
        int xlo = (t > 43) ? (t - 41) / 3 : 0;   // ceil((t-43)/3), clamped
        int xhi = t / 3; if (xhi > 43) xhi = 43;
        int x2  = xlo + s;
        bool active = (x2 <= xhi);
        float v = 0.f; int cell = 0;
        if (active) {
            int y2 = t - 3 * x2;                 // guaranteed in [0,43]
            int y = y2 + DP, x = x2 + DP;
            cell = y * SZ + x;
            const float* gb = g + bl * GS;
            v = gb[cell];                        // own slot still holds in[y,x]
            #pragma unroll
            for (int k = 0; k < 12; ++k) {
                int dy = E_DY[k], dx = E_DX[k];
                int nc = cell + dy * SZ + dx;    // always in [0,NC) here
                bool ok = is_in(y + dy) && is_in(x + dx);
                float wv = w[nc * 25 + (DP - dy) * 5 + (DP - dx)];
                v += (ok ? wv : 0.f) * gb[nc];
            }
        }
        // step-t writes only hit step-t centers, which no step-t task reads
        // (same-t cells are >=3 apart) -> single barrier per step.
        if (active) g[bl * GS + cell] = v;
        __syncthreads();
    }

    // ---- finalize ----
    // interior p: out = V(p)*w_p[2,2] + sum over 12 later interior nbrs
    // border  p: out = in(p) + sum over ALL interior nbrs within dist 2
    const int L_DY[12] = { 1, 2, -2,-1, 0, 1, 2, -2,-1, 0, 1, 2};
    const int L_DX[12] = { 0, 0,  1, 1, 1, 1, 1,  2, 2, 2, 2, 2};

    for (int chunk = 0; chunk < NC / NT; ++chunk) {
        int c = chunk * NT + tid;
        int y = c / SZ, x = c - y * SZ;
        if (is_in(y) && is_in(x)) {
            float wt[13]; int ic[13];
            wt[0] = w[c * 25 + 12];              // own center weight w[2][2]
            ic[0] = c;
            #pragma unroll
            for (int k = 0; k < 12; ++k) {
                int dy = L_DY[k], dx = L_DX[k];
                int nc = c + dy * SZ + dx;       // always in [0,NC) for interior c
                bool ok = is_in(y + dy) && is_in(x + dx);
                wt[k + 1] = ok ? w[nc * 25 + (DP - dy) * 5 + (DP - dx)] : 0.f;
                ic[k + 1] = ok ? nc : c;
            }
            for (int b = 0; b < NB; ++b) {
                const float* gb = g + b * GS;
                float o = 0.f;
                #pragma unroll
                for (int k = 0; k < 13; ++k) o += wt[k] * gb[ic[k]];
                out[(b0 + b) * NC + c] = o;
            }
        } else {
            float wt[24]; int ic[24];
            int k = 0;
            #pragma unroll
            for (int dy = -2; dy <= 2; ++dy) {
                #pragma unroll
                for (int dx = -2; dx <= 2; ++dx) {
                    if (dy == 0 && dx == 0) continue;
                    bool ok = is_in(y + dy) && is_in(x + dx);
                    int nc = ok ? (c + dy * SZ + dx) : c;   // clamp addr when OOB
                    wt[k] = ok ? w[nc * 25 + (DP - dy) * 5 + (DP - dx)] : 0.f;
                    ic[k] = nc;
                    ++k;
                }
            }
            for (int b = 0; b < NB; ++b) {
                const float* gb = g + b * GS;
                float o = gb[c];                 // border slot = untouched input
                #pragma unroll
                for (int kk = 0; kk < 24; ++kk) o += wt[kk] * gb[ic[kk]];
                out[(b0 + b) * NC + c] = o;
            }
        }
    }
}

extern "C" void kernel_launch(void* const* d_in, const int* in_sizes, int n_in,
                              void* d_out, int out_size, void* d_ws, size_t ws_size,
                              hipStream_t stream)
{
    const float* in = (const float*)d_in[0];
    const float* w  = (const float*)d_in[1];
    float* out = (float*)d_out;

    const int batch   = in_sizes[0] / NC;        // 8192
    const int nblocks = batch / NB;              // 1024
    const size_t lds  = (size_t)NB * GS * sizeof(float);  // 73,856 B

    ca_kernel<<<nblocks, NT, lds, stream>>>(in, w, out);
}

// Round 2
// 391.381 us; speedup vs baseline: 1.6083x; 1.6083x over previous
//
#include <hip/hip_runtime.h>

// Sequential 5x5 cellular scatter, 48x48, 8192 batches, fp32.
// R2 restructure vs R1:
//  - All weight masking/address math hoisted into prep_kernel, which packs
//    per-cell coefficient tables into d_ws:
//      WF[c][12] : gather weights for the 12 earlier neighbors (forward phase)
//      FI[c][16] : [0]=own center weight, [1..12]=later-neighbor weights (interior finalize)
//      FB[c][24] : all-24-neighbor masked weights (border finalize)
//    Hot loop is now 3x float4 table loads + 13 ds_read (imm offsets) + 12 FMA + 1 ds_write.
//  - 1-wave blocks (64 thr = 4 batches x 16 wavefront slots): no __syncthreads
//    anywhere — single-wave program order + compiler lgkmcnt gives write(t) ->
//    read(t+1) ordering, and avoids the vmcnt(0) drain a barrier forces.
//    Same-t cells are >=3 apart (commute) and reads precede the write in
//    program order, so the wavefront schedule t=(y-2)+3*(x-2) stays exact.
//  - LDS 36.9 KB/block -> 4 blocks/CU, 2048 blocks = 2 occupancy rounds.

#define SZ 48
#define DP 2
#define NC (SZ * SZ)          // 2304
#define NBATCH 4              // batches per workgroup
#define GS 2308               // LDS grid stride (floats); 2308 % 32 == 4
#define NSTEP 173             // t = (y-2) + 3*(x-2), max 172
#define NT 64                 // one wave

#define WF_STRIDE 12
#define FI_STRIDE 16
#define FB_STRIDE 24
// ws layout (floats): WF[NC*12] | FI[NC*16] | FB[NC*24]  = NC*52*4 B = 479,232 B

__device__ __forceinline__ bool is_in(int v) {
    return (unsigned)(v - DP) <= (unsigned)(SZ - 2 * DP - 1);   // v in [2,45]
}

// ---- table construction: one thread per cell ----
__global__ void prep_kernel(const float* __restrict__ w, float* __restrict__ ws)
{
    int c = blockIdx.x * 256 + threadIdx.x;
    if (c >= NC) return;
    int y = c / SZ, x = c - y * SZ;
    float* WF = ws;
    float* FI = ws + NC * WF_STRIDE;
    float* FB = FI + NC * FI_STRIDE;
    bool ci = is_in(y) && is_in(x);

    const int edy[12] = {-2,-1, 0, 1, 2, -2,-1, 0, 1, 2, -2,-1};
    const int edx[12] = {-2,-2,-2,-2,-2, -1,-1,-1,-1,-1,  0, 0};
    #pragma unroll
    for (int k = 0; k < 12; ++k) {
        int dy = edy[k], dx = edx[k];
        float v = 0.f;
        if (ci && is_in(y + dy) && is_in(x + dx)) {
            int nc = c + dy * SZ + dx;
            v = w[nc * 25 + (DP - dy) * 5 + (DP - dx)];
        }
        WF[c * WF_STRIDE + k] = v;
    }

    FI[c * FI_STRIDE + 0] = ci ? w[c * 25 + 12] : 0.f;
    const int ldy[12] = { 1, 2, -2,-1, 0, 1, 2, -2,-1, 0, 1, 2};
    const int ldx[12] = { 0, 0,  1, 1, 1, 1, 1,  2, 2, 2, 2, 2};
    #pragma unroll
    for (int k = 0; k < 12; ++k) {
        int dy = ldy[k], dx = ldx[k];
        float v = 0.f;
        if (is_in(y + dy) && is_in(x + dx)) {
            int nc = c + dy * SZ + dx;
            v = w[nc * 25 + (DP - dy) * 5 + (DP - dx)];
        }
        FI[c * FI_STRIDE + 1 + k] = v;
    }
    #pragma unroll
    for (int k = 13; k < FI_STRIDE; ++k) FI[c * FI_STRIDE + k] = 0.f;

    int k = 0;
    #pragma unroll
    for (int dy = -2; dy <= 2; ++dy) {
        #pragma unroll
        for (int dx = -2; dx <= 2; ++dx) {
            if (dy == 0 && dx == 0) continue;
            float v = 0.f;
            if (is_in(y + dy) && is_in(x + dx)) {
                int nc = c + dy * SZ + dx;
                v = w[nc * 25 + (DP - dy) * 5 + (DP - dx)];
            }
            FB[c * FB_STRIDE + k] = v;
            ++k;
        }
    }
}

__global__ __launch_bounds__(NT)
void ca_kernel(const float* __restrict__ in, const float* __restrict__ ws,
               float* __restrict__ out)
{
    __shared__ float g[NBATCH * GS];   // 36,928 B
    const int tid = threadIdx.x;
    const int b0  = blockIdx.x * NBATCH;
    const float* WF = ws;
    const float* FI = ws + NC * WF_STRIDE;
    const float* FB = FI + NC * FI_STRIDE;

    // ---- load 4 grids into LDS, float4 coalesced (no barrier: single wave) ----
    {
        const float4* in4 = (const float4*)(in + (size_t)b0 * NC);
        for (int i = tid; i < NBATCH * NC / 4; i += NT) {
            int b = i / (NC / 4), c4 = i - b * (NC / 4);
            *(float4*)&g[b * GS + c4 * 4] = in4[i];
        }
    }

    const int bl = tid & (NBATCH - 1);   // batch lane 0..3
    const int s  = tid >> 2;             // wavefront slot 0..15
    float* gb = g + bl * GS;

    // ---- forward wavefront recurrence ----
    for (int t = 0; t < NSTEP; ++t) {
        int xlo = (t > 43) ? (t - 41) / 3 : 0;   // ceil((t-43)/3)
        int xhi = t / 3; if (xhi > 43) xhi = 43;
        int x2  = xlo + s;
        if (x2 <= xhi) {
            int y2   = t - 3 * x2;               // in [0,43]
            int cell = (y2 + DP) * SZ + (x2 + DP);
            const float4* wfp = (const float4*)(WF + cell * WF_STRIDE);
            float4 w0 = wfp[0], w1 = wfp[1], w2 = wfp[2];
            const float* p = gb + cell - 98;     // all 13 reads at non-neg imm offsets
            // k: (dy,dx) -> p offset: (-2,-2)=0 (-1,-2)=48 (0,-2)=96 (1,-2)=144 (2,-2)=192
            //               (-2,-1)=1 (-1,-1)=49 (0,-1)=97 (1,-1)=145 (2,-1)=193
            //               (-2, 0)=2 (-1, 0)=50  center=98
            float a0 = w0.x * p[0]   + w0.y * p[48]  + w0.z * p[96] + w0.w * p[144];
            float a1 = w1.x * p[192] + w1.y * p[1]   + w1.z * p[49] + w1.w * p[97];
            float a2 = w2.x * p[145] + w2.y * p[193] + w2.z * p[2]  + w2.w * p[50];
            gb[cell] = p[98] + a0 + a1 + a2;
        }
        // no __syncthreads: 1-wave block, program order + lgkmcnt orders LDS ops
    }

    // ---- finalize: out = center-term + later-scatter (interior) / input + all-nbr (border) ----
    for (int i = 0; i < NC / NT; ++i) {          // 36 cells per thread
        int c = i * NT + tid;
        int y = c / SZ, x = c - y * SZ;
        if (is_in(y) && is_in(x)) {
            const float4* fi = (const float4*)(FI + c * FI_STRIDE);
            float4 f0 = fi[0], f1 = fi[1], f2 = fi[2], f3 = fi[3];
            #pragma unroll
            for (int b = 0; b < NBATCH; ++b) {
                const float* p = g + b * GS + c - 95;
                // center=95; later offsets: (1,0)=143 (2,0)=191 (-2,1)=0 (-1,1)=48 (0,1)=96
                // (1,1)=144 (2,1)=192 (-2,2)=1 (-1,2)=49 (0,2)=97 (1,2)=145 (2,2)=193
                float o = f0.x * p[95]  + f0.y * p[143] + f0.z * p[191] + f0.w * p[0]
                        + f1.x * p[48]  + f1.y * p[96]  + f1.z * p[144] + f1.w * p[192]
                        + f2.x * p[1]   + f2.y * p[49]  + f2.z * p[97]  + f2.w * p[145]
                        + f3.x * p[193];
                out[(size_t)(b0 + b) * NC + c] = o;
            }
        } else {
            float fw[24];
            #pragma unroll
            for (int k2 = 0; k2 < 24; k2 += 4) {
                float4 q = *(const float4*)(FB + c * FB_STRIDE + k2);
                fw[k2] = q.x; fw[k2 + 1] = q.y; fw[k2 + 2] = q.z; fw[k2 + 3] = q.w;
            }
            int idx[24];
            {
                int k = 0;
                #pragma unroll
                for (int dy = -2; dy <= 2; ++dy) {
                    #pragma unroll
                    for (int dx = -2; dx <= 2; ++dx) {
                        if (dy == 0 && dx == 0) continue;
                        int yy = y + dy, xx = x + dx;
                        // weight is 0 when neighbor not interior; clamp addr when off-grid
                        idx[k] = ((unsigned)yy < SZ && (unsigned)xx < SZ) ? (c + dy * SZ + dx) : c;
                        ++k;
                    }
                }
            }
            #pragma unroll
            for (int b = 0; b < NBATCH; ++b) {
                const float* gbp = g + b * GS;
                float o = gbp[c];                // border center untouched = in(p)
                #pragma unroll
                for (int k2 = 0; k2 < 24; ++k2) o += fw[k2] * gbp[idx[k2]];
                out[(size_t)(b0 + b) * NC + c] = o;
            }
        }
    }
}

extern "C" void kernel_launch(void* const* d_in, const int* in_sizes, int n_in,
                              void* d_out, int out_size, void* d_ws, size_t ws_size,
                              hipStream_t stream)
{
    const float* in = (const float*)d_in[0];
    const float* w  = (const float*)d_in[1];
    float* out = (float*)d_out;
    float* ws  = (float*)d_ws;   // needs NC*52*4 = 479,232 B

    const int batch   = in_sizes[0] / NC;    // 8192
    const int nblocks = batch / NBATCH;      // 2048

    prep_kernel<<<(NC + 255) / 256, 256, 0, stream>>>(w, ws);
    ca_kernel<<<nblocks, NT, 0, stream>>>(in, ws, out);
}

// Round 4
// 275.965 us; speedup vs baseline: 2.2810x; 1.4182x over previous
//
#include <hip/hip_runtime.h>

// Sequential 5x5 cellular scatter, 48x48, 8192 batches, fp32.
// R4 = R3 with the macro-pasting build break fixed (inline functions instead
// of ##-macros). Strategy recap:
//  - Forward weights step-major WFseq[t][slot][12]; software pipeline with
//    4 register sets (prefetch distance 4 steps ~ 800-1300cy of cover).
//  - Finalize tables compacted + linearly indexed (FIc[1936][16],
//    FBc[368][24]), prefetched one iteration ahead.
//  - Zeroed +-104-float LDS halo makes border finalize reads unconditional.
//  - 64-thread (1-wave) blocks, no barriers; 4 batches/block; 4 blocks/CU
//    (LDS-capped), 2048 blocks = 2 occupancy rounds.

#define SZ 48
#define DP 2
#define NC (SZ * SZ)        // 2304
#define NBATCH 4
#define GS 2308             // LDS grid stride (floats)
#define PADH 104            // zeroed halo floats each side
#define NSTEP 173
#define TSTEPS 180          // padded for prefetch overrun
#define NT 64

#define NINT 1936
#define NINT_ALLOC 2048
#define NBOR 368
#define NBOR_ALLOC 448

#define WF_FLOATS (TSTEPS * 16 * 12)        // 34560
#define FI_FLOATS (NINT_ALLOC * 16)         // 32768
#define FB_FLOATS (NBOR_ALLOC * 24)         // 10752
// ws total: 78080 floats = 312,320 B

__device__ __forceinline__ bool is_in(int v) {
    return (unsigned)(v - DP) <= (unsigned)(SZ - 2 * DP - 1);   // [2,45]
}

// ---------------- table construction ----------------
__global__ void prep_kernel(const float* __restrict__ w, float* __restrict__ ws)
{
    int id = blockIdx.x * 256 + threadIdx.x;
    float* WFseq = ws;
    float* FIc   = ws + WF_FLOATS;
    float* FBc   = FIc + FI_FLOATS;

    if (id < TSTEPS * 16) {
        int t = id >> 4, s = id & 15;
        float vals[12];
        #pragma unroll
        for (int k = 0; k < 12; ++k) vals[k] = 0.f;
        if (t < NSTEP) {
            int xlo = (t > 43) ? (t - 41) / 3 : 0;
            int xhi = t / 3; if (xhi > 43) xhi = 43;
            int x2 = xlo + s;
            if (x2 <= xhi) {
                int y2 = t - 3 * x2;
                int y = y2 + DP, x = x2 + DP, c = y * SZ + x;
                const int edy[12] = {-2,-1, 0, 1, 2, -2,-1, 0, 1, 2, -2,-1};
                const int edx[12] = {-2,-2,-2,-2,-2, -1,-1,-1,-1,-1,  0, 0};
                #pragma unroll
                for (int k = 0; k < 12; ++k) {
                    int dy = edy[k], dx = edx[k];
                    if (is_in(y + dy) && is_in(x + dx)) {
                        int nc = c + dy * SZ + dx;
                        vals[k] = w[nc * 25 + (DP - dy) * 5 + (DP - dx)];
                    }
                }
            }
        }
        float* o = WFseq + id * 12;
        #pragma unroll
        for (int k = 0; k < 12; ++k) o[k] = vals[k];
        return;
    }
    int id2 = id - TSTEPS * 16;
    if (id2 < NINT_ALLOC) {
        float vals[16];
        #pragma unroll
        for (int k = 0; k < 16; ++k) vals[k] = 0.f;
        if (id2 < NINT) {
            int y2 = id2 / 44, x2 = id2 - y2 * 44;
            int y = y2 + DP, x = x2 + DP, c = y * SZ + x;
            vals[0] = w[c * 25 + 12];
            const int ldy[12] = { 1, 2, -2,-1, 0, 1, 2, -2,-1, 0, 1, 2};
            const int ldx[12] = { 0, 0,  1, 1, 1, 1, 1,  2, 2, 2, 2, 2};
            #pragma unroll
            for (int k = 0; k < 12; ++k) {
                int dy = ldy[k], dx = ldx[k];
                if (is_in(y + dy) && is_in(x + dx)) {
                    int nc = c + dy * SZ + dx;
                    vals[1 + k] = w[nc * 25 + (DP - dy) * 5 + (DP - dx)];
                }
            }
        }
        float* o = FIc + id2 * 16;
        #pragma unroll
        for (int k = 0; k < 16; ++k) o[k] = vals[k];
        return;
    }
    int id3 = id2 - NINT_ALLOC;
    if (id3 < NBOR_ALLOC) {
        float vals[24];
        #pragma unroll
        for (int k = 0; k < 24; ++k) vals[k] = 0.f;
        if (id3 < NBOR) {
            int y, x;
            if (id3 < 96)       { y = id3 / 48;             x = id3 - (id3 / 48) * 48; }
            else if (id3 < 192) { int j = id3 - 96;  y = 46 + j / 48; x = j - (j / 48) * 48; }
            else                { int j = id3 - 192; y = 2 + (j >> 2); int q = j & 3; x = q + (q >= 2 ? 44 : 0); }
            int c = y * SZ + x;
            int k = 0;
            #pragma unroll
            for (int dy = -2; dy <= 2; ++dy) {
                #pragma unroll
                for (int dx = -2; dx <= 2; ++dx) {
                    if (dy == 0 && dx == 0) continue;
                    if (is_in(y + dy) && is_in(x + dx)) {
                        int nc = c + dy * SZ + dx;
                        vals[k] = w[nc * 25 + (DP - dy) * 5 + (DP - dx)];
                    }
                    ++k;
                }
            }
        }
        float* o = FBc + id3 * 24;
        #pragma unroll
        for (int k = 0; k < 24; ++k) o[k] = vals[k];
    }
}

// one wavefront step for this thread's (slot s, batch lane) pair
__device__ __forceinline__ void do_step(int tt, int s, float* gb,
                                        float4 w0, float4 w1, float4 w2)
{
    int xlo = (tt > 43) ? (tt - 41) / 3 : 0;
    int xhi = tt / 3; if (xhi > 43) xhi = 43;
    int x2 = xlo + s;
    if (x2 <= xhi) {
        int cell = (tt - 3 * x2 + DP) * SZ + x2 + DP;
        const float* p = gb + cell - 98;
        // (dy,dx) -> offset: (-2,-2)=0 (-1,-2)=48 (0,-2)=96 (1,-2)=144 (2,-2)=192
        //            (-2,-1)=1 (-1,-1)=49 (0,-1)=97 (1,-1)=145 (2,-1)=193
        //            (-2,0)=2 (-1,0)=50  center=98
        float a0 = w0.x * p[0]   + w0.y * p[48]  + w0.z * p[96] + w0.w * p[144];
        float a1 = w1.x * p[192] + w1.y * p[1]   + w1.z * p[49] + w1.w * p[97];
        float a2 = w2.x * p[145] + w2.y * p[193] + w2.z * p[2]  + w2.w * p[50];
        gb[cell] = p[98] + a0 + a1 + a2;
    }
}

__device__ __forceinline__ void loadw(const float* wfbase, int tt,
                                      float4& w0, float4& w1, float4& w2)
{
    const float4* q = (const float4*)(wfbase + tt * 192);
    w0 = q[0]; w1 = q[1]; w2 = q[2];
}

// ---------------- main kernel ----------------
__global__ __launch_bounds__(NT)
void ca_kernel(const float* __restrict__ in, const float* __restrict__ ws,
               float* __restrict__ out)
{
    __shared__ float gmem[PADH + NBATCH * GS + PADH];
    float* g = gmem + PADH;
    const int tid = threadIdx.x;
    const int b0  = blockIdx.x * NBATCH;

    // zero halos, load 4 grids (single wave: no barriers anywhere)
    for (int i = tid; i < PADH; i += NT) { gmem[i] = 0.f; gmem[PADH + NBATCH * GS + i] = 0.f; }
    #pragma unroll
    for (int b = 0; b < NBATCH; ++b) {
        const float4* src = (const float4*)(in + (size_t)(b0 + b) * NC);
        float4* dst = (float4*)(g + b * GS);
        for (int i = tid; i < NC / 4; i += NT) dst[i] = src[i];
    }

    const int bl = tid & (NBATCH - 1);
    const int s  = tid >> 2;
    float* gb = g + bl * GS;
    const float* wfbase = ws + s * 12;       // step stride = 16*12 = 192 floats

    float4 A0, A1, A2, B0, B1, B2, C0, C1, C2, D0, D1, D2;
    loadw(wfbase, 0, A0, A1, A2);
    loadw(wfbase, 1, B0, B1, B2);
    loadw(wfbase, 2, C0, C1, C2);
    loadw(wfbase, 3, D0, D1, D2);
    for (int t = 0; t < 176; t += 4) {       // steps 173..175 have no active slots
        do_step(t + 0, s, gb, A0, A1, A2);  loadw(wfbase, t + 4, A0, A1, A2);
        do_step(t + 1, s, gb, B0, B1, B2);  loadw(wfbase, t + 5, B0, B1, B2);
        do_step(t + 2, s, gb, C0, C1, C2);  loadw(wfbase, t + 6, C0, C1, C2);
        do_step(t + 3, s, gb, D0, D1, D2);  loadw(wfbase, t + 7, D0, D1, D2);
    }

    // ---------------- finalize: interior (prefetch distance 1) ----------------
    const float* FIc = ws + WF_FLOATS;
    const float* FBc = FIc + FI_FLOATS;

    {
        const float4* fp = (const float4*)(FIc + tid * 16);
        float4 f0 = fp[0], f1 = fp[1], f2 = fp[2], f3 = fp[3];
        for (int it = 0; it < 31; ++it) {
            int idx = it * NT + tid;
            const float4* np = (const float4*)(FIc + (idx + NT) * 16);
            float4 n0 = np[0], n1 = np[1], n2 = np[2], n3 = np[3];
            if (idx < NINT) {
                int y2 = idx / 44, x2 = idx - y2 * 44;
                int c = (y2 + DP) * SZ + x2 + DP;
                #pragma unroll
                for (int b = 0; b < NBATCH; ++b) {
                    const float* p = g + b * GS + c - 95;
                    // center=95; later: (1,0)=143 (2,0)=191 (-2,1)=0 (-1,1)=48 (0,1)=96
                    // (1,1)=144 (2,1)=192 (-2,2)=1 (-1,2)=49 (0,2)=97 (1,2)=145 (2,2)=193
                    float o = f0.x * p[95]  + f0.y * p[143] + f0.z * p[191] + f0.w * p[0]
                            + f1.x * p[48]  + f1.y * p[96]  + f1.z * p[144] + f1.w * p[192]
                            + f2.x * p[1]   + f2.y * p[49]  + f2.z * p[97]  + f2.w * p[145]
                            + f3.x * p[193];
                    out[(size_t)(b0 + b) * NC + c] = o;
                }
            }
            f0 = n0; f1 = n1; f2 = n2; f3 = n3;
        }
    }

    // ---------------- finalize: border ----------------
    {
        const float4* fp = (const float4*)(FBc + tid * 24);
        float4 f0 = fp[0], f1 = fp[1], f2 = fp[2], f3 = fp[3], f4 = fp[4], f5 = fp[5];
        for (int it = 0; it < 6; ++it) {
            int idx = it * NT + tid;
            const float4* np = (const float4*)(FBc + (idx + NT) * 24);
            float4 n0 = np[0], n1 = np[1], n2 = np[2], n3 = np[3], n4 = np[4], n5 = np[5];
            if (idx < NBOR) {
                int y, x;
                if (idx < 96)       { y = idx / 48;            x = idx - (idx / 48) * 48; }
                else if (idx < 192) { int j = idx - 96;  y = 46 + j / 48; x = j - (j / 48) * 48; }
                else                { int j = idx - 192; y = 2 + (j >> 2); int q = j & 3; x = q + (q >= 2 ? 44 : 0); }
                int c = y * SZ + x;
                #pragma unroll
                for (int b = 0; b < NBATCH; ++b) {
                    const float* p = g + b * GS + c - 98;   // halo makes all reads safe
                    float o = p[98]
                        + f0.x * p[0]   + f0.y * p[1]   + f0.z * p[2]   + f0.w * p[3]
                        + f1.x * p[4]   + f1.y * p[48]  + f1.z * p[49]  + f1.w * p[50]
                        + f2.x * p[51]  + f2.y * p[52]  + f2.z * p[96]  + f2.w * p[97]
                        + f3.x * p[99]  + f3.y * p[100] + f3.z * p[144] + f3.w * p[145]
                        + f4.x * p[146] + f4.y * p[147] + f4.z * p[148] + f4.w * p[192]
                        + f5.x * p[193] + f5.y * p[194] + f5.z * p[195] + f5.w * p[196];
                    out[(size_t)(b0 + b) * NC + c] = o;
                }
            }
            f0 = n0; f1 = n1; f2 = n2; f3 = n3; f4 = n4; f5 = n5;
        }
    }
}

extern "C" void kernel_launch(void* const* d_in, const int* in_sizes, int n_in,
                              void* d_out, int out_size, void* d_ws, size_t ws_size,
                              hipStream_t stream)
{
    const float* in = (const float*)d_in[0];
    const float* w  = (const float*)d_in[1];
    float* out = (float*)d_out;
    float* ws  = (float*)d_ws;   // needs 312,320 B

    const int batch   = in_sizes[0] / NC;    // 8192
    const int nblocks = batch / NBATCH;      // 2048

    prep_kernel<<<21, 256, 0, stream>>>(w, ws);   // 5376 threads cover all tables
    ca_kernel<<<nblocks, NT, 0, stream>>>(in, ws, out);
}